// Round 12
// baseline (455.513 us; speedup 1.0000x reference)
//
#include <hip/hip_runtime.h>
#include <hip/hip_bf16.h>
#include <cstdint>
#include <cstddef>

// Problem constants
constexpr int B_  = 2;
constexpr int T_  = 2048;
constexpr int D_  = 2048;
constexpr int H_  = 8;
constexpr int HD_ = 128;
constexpr int C_  = 1024;   // H*HD
constexpr int BT_ = 64;
constexpr int NT_ = 32;     // T/BT
constexpr int M_  = 4096;   // B*T
constexpr float EPS_RMS = 1.1920929e-07f;

typedef __bf16 bf16x8 __attribute__((ext_vector_type(8)));
typedef float f32x4 __attribute__((ext_vector_type(4)));

typedef const __attribute__((address_space(1))) unsigned int* gptr_t;
typedef __attribute__((address_space(3))) unsigned int* lptr_t;

__device__ __forceinline__ void gload16(const void* g, void* l) {
  __builtin_amdgcn_global_load_lds((gptr_t)g, (lptr_t)l, 16, 0, 0);
}

// Swizzled byte offset into a [64][128] bf16 LDS tile (row stride 256 B).
#define SWZ(row, cbytes) ((((row) * 256) + (cbytes)) ^ (((row) & 7) << 4))
// Swizzled byte offset into a [*][64] bf16 LDS tile (row stride 128 B).
#define TSWZ(row, cbytes) ((((row) * 128) + (cbytes)) ^ (((row) & 7) << 4))

// ---------------------------------------------------------------------------
// gemm8p: 256x256-tile, BK=64, 8-wave, 8-phase counted-vmcnt GEMM.
// (round-2 verified form)
// ---------------------------------------------------------------------------

#define LD_A(base, mq, dst) do { \
    _Pragma("unroll") for (int i_ = 0; i_ < 4; ++i_) \
      _Pragma("unroll") for (int k_ = 0; k_ < 2; ++k_) \
        dst[i_][k_] = *(const bf16x8*)((base) + (mq) * 8192 + i_ * 2048 + k_ * 1024); \
  } while (0)

#define LD_B(base, nq, dst) do { \
    _Pragma("unroll") for (int j_ = 0; j_ < 2; ++j_) \
      _Pragma("unroll") for (int k_ = 0; k_ < 2; ++k_) \
        dst[j_][k_] = *(const bf16x8*)((base) + (nq) * 4096 + j_ * 2048 + k_ * 1024); \
  } while (0)

#define MM_Q(afr, bfr, mq, nq) do { \
    _Pragma("unroll") for (int i_ = 0; i_ < 4; ++i_) \
      _Pragma("unroll") for (int j_ = 0; j_ < 2; ++j_) \
        _Pragma("unroll") for (int k_ = 0; k_ < 2; ++k_) \
          acc[(mq) * 4 + i_][(nq) * 2 + j_] = __builtin_amdgcn_mfma_f32_16x16x32_bf16( \
              afr[i_][k_], bfr[j_][k_], acc[(mq) * 4 + i_][(nq) * 2 + j_], 0, 0, 0); \
  } while (0)

#define STAGE(src, grow0, kc, loff) do { \
    gload16((src) + (size_t)((grow0) + sr0) * 2048 + (kc) + sc0, smem + (loff) + tid * 16); \
    gload16((src) + (size_t)((grow0) + sr1) * 2048 + (kc) + sc1, smem + (loff) + 8192 + tid * 16); \
  } while (0)

#define PH_SYNC_PRE do { \
    __builtin_amdgcn_s_barrier(); \
    asm volatile("s_waitcnt lgkmcnt(0)" ::: "memory"); \
    __builtin_amdgcn_sched_barrier(0); \
    __builtin_amdgcn_s_setprio(1); \
  } while (0)

#define PH_SYNC_POST do { \
    __builtin_amdgcn_s_setprio(0); \
    __builtin_amdgcn_sched_barrier(0); \
    __builtin_amdgcn_s_barrier(); \
  } while (0)

#define PH_SYNC_POST_VM4 do { \
    __builtin_amdgcn_s_setprio(0); \
    __builtin_amdgcn_sched_barrier(0); \
    asm volatile("s_waitcnt vmcnt(4)" ::: "memory"); \
    __builtin_amdgcn_s_barrier(); \
  } while (0)

#define PH_SYNC_POST_VM0 do { \
    __builtin_amdgcn_s_setprio(0); \
    __builtin_amdgcn_sched_barrier(0); \
    asm volatile("s_waitcnt vmcnt(0)" ::: "memory"); \
    __builtin_amdgcn_s_barrier(); \
  } while (0)

__global__ __launch_bounds__(512, 1) void gemm8p(
    const __hip_bfloat16* __restrict__ A_, const __hip_bfloat16* __restrict__ B_,
    __hip_bfloat16* __restrict__ pre, __hip_bfloat16* __restrict__ adb,
    __hip_bfloat16* __restrict__ gdb) {
  __shared__ alignas(16) char smem[131072];
  const int tid = threadIdx.x, lane = tid & 63;
  const int wid = tid >> 6;
  const int wm = (wid >> 2) * 128, wn = (wid & 3) * 64;
  const int lr = lane & 15, lg = lane >> 4;

  const int bid = blockIdx.x;
  const int swz = (bid & 7) * 26 + (bid >> 3);
  const int mt = swz / 13, nt = swz % 13;
  const int m0 = mt * 256, n0g = nt * 256;

  int ob0 = tid * 16;         ob0 ^= ((ob0 >> 9) & 1) << 5;
  int ob1 = (tid + 512) * 16; ob1 ^= ((ob1 >> 9) & 1) << 5;
  const int sr0 = ((ob0 >> 11) << 4) + ((ob0 >> 6) & 15);
  const int sc0 = ((ob0 >> 10) & 1) * 32 + ((ob0 & 63) >> 1);
  const int sr1 = ((ob1 >> 11) << 4) + ((ob1 >> 6) & 15);
  const int sc1 = ((ob1 >> 10) & 1) * 32 + ((ob1 & 63) >> 1);

  const int foff = lr * 64 + ((lg * 16) ^ ((lr & 8) << 2));
  const int bq = (wn & 64) * 128;
  const char* a0base = smem + (wm >> 7) * 16384 + foff;
  const char* a1base = smem + 65536 + (wm >> 7) * 16384 + foff;
  const char* b0base = smem + 32768 + (wn >> 7) * 16384 + bq + foff;
  const char* b1base = smem + 98304 + (wn >> 7) * 16384 + bq + foff;

  f32x4 acc[8][4];
#pragma unroll
  for (int i = 0; i < 8; ++i)
#pragma unroll
    for (int j = 0; j < 4; ++j) acc[i][j] = (f32x4)(0.f);

  bf16x8 a[4][2], b01[2][2], b23[2][2];

  STAGE(A_, m0,        0, 0);
  STAGE(A_, m0 + 128,  0, 16384);
  STAGE(B_, n0g,       0, 32768);
  STAGE(B_, n0g + 128, 0, 32768 + 16384);
  STAGE(B_, n0g,       64, 98304);
  STAGE(B_, n0g + 128, 64, 98304 + 16384);
  asm volatile("s_waitcnt vmcnt(4)" ::: "memory");
  __builtin_amdgcn_s_barrier();

#pragma unroll 1
  for (int it = 0; it < 15; ++it) {
    const int kA1 = (2 * it + 1) * 64;
    const int kN2 = (2 * it + 2) * 64;
    const int kB3 = (2 * it + 3) * 64;
    LD_A(a0base, 0, a);
    LD_B(b0base, 0, b01);
    STAGE(A_, m0, kA1, 65536);
    PH_SYNC_PRE; MM_Q(a, b01, 0, 0); PH_SYNC_POST;
    LD_B(b0base, 1, b23);
    STAGE(A_, m0 + 128, kA1, 65536 + 16384);
    PH_SYNC_PRE; MM_Q(a, b23, 0, 1); PH_SYNC_POST;
    LD_A(a0base, 1, a);
    STAGE(B_, n0g, kN2, 32768);
    PH_SYNC_PRE; MM_Q(a, b23, 1, 1); PH_SYNC_POST;
    STAGE(B_, n0g + 128, kN2, 32768 + 16384);
    PH_SYNC_PRE; MM_Q(a, b01, 1, 0); PH_SYNC_POST_VM4;
    LD_A(a1base, 0, a);
    LD_B(b1base, 0, b01);
    STAGE(A_, m0, kN2, 0);
    PH_SYNC_PRE; MM_Q(a, b01, 0, 0); PH_SYNC_POST;
    LD_B(b1base, 1, b23);
    STAGE(A_, m0 + 128, kN2, 16384);
    PH_SYNC_PRE; MM_Q(a, b23, 0, 1); PH_SYNC_POST;
    LD_A(a1base, 1, a);
    STAGE(B_, n0g, kB3, 98304);
    PH_SYNC_PRE; MM_Q(a, b23, 1, 1); PH_SYNC_POST;
    STAGE(B_, n0g + 128, kB3, 98304 + 16384);
    PH_SYNC_PRE; MM_Q(a, b01, 1, 0); PH_SYNC_POST_VM4;
  }

  {
    const int kT = 1984;
    LD_A(a0base, 0, a);
    LD_B(b0base, 0, b01);
    STAGE(A_, m0, kT, 65536);
    PH_SYNC_PRE; MM_Q(a, b01, 0, 0); PH_SYNC_POST;
    LD_B(b0base, 1, b23);
    STAGE(A_, m0 + 128, kT, 65536 + 16384);
    PH_SYNC_PRE; MM_Q(a, b23, 0, 1); PH_SYNC_POST;
    LD_A(a0base, 1, a);
    PH_SYNC_PRE; MM_Q(a, b23, 1, 1); PH_SYNC_POST;
    PH_SYNC_PRE; MM_Q(a, b01, 1, 0); PH_SYNC_POST_VM0;
    LD_A(a1base, 0, a);
    LD_B(b1base, 0, b01);
    MM_Q(a, b01, 0, 0);
    LD_B(b1base, 1, b23);
    MM_Q(a, b23, 0, 1);
    LD_A(a1base, 1, a);
    MM_Q(a, b23, 1, 1);
    MM_Q(a, b01, 1, 0);
  }

#pragma unroll
  for (int mf = 0; mf < 8; ++mf) {
    const int row0 = m0 + wm + mf * 16 + lg * 4;
#pragma unroll
    for (int nf = 0; nf < 4; ++nf) {
      const int c = n0g + wn + nf * 16 + lr;
#pragma unroll
      for (int r = 0; r < 4; ++r) {
        const __hip_bfloat16 v = __float2bfloat16(acc[mf][nf][r]);
        const size_t rr = (size_t)(row0 + r);
        if (c < 3072)      pre[rr * 3072 + c] = v;
        else if (c < 3200) adb[rr * 128 + (c - 3072)] = v;
        else               gdb[rr * 128 + (c - 3200)] = v;
      }
    }
  }
}

// ---------------------------------------------------------------------------
// gemm_bf16k (Wo path): C[M,N] = A[M,K] @ Bt[N,K]^T, BK=64, TSWZ-swizzled
// LDS tiles staged via pre-swizzled global sources (linear gload_lds dest).
// MFMA order identical to the BK=32 form (two sub-steps kk=0,32).
// ---------------------------------------------------------------------------
template <typename OutT>
__global__ __launch_bounds__(256) void gemm_bf16k(
    const __hip_bfloat16* __restrict__ A, const __hip_bfloat16* __restrict__ Bt,
    OutT* __restrict__ C, int N, int K) {
  __shared__ alignas(16) char sA[128 * 64 * 2];
  __shared__ alignas(16) char sB[128 * 64 * 2];
  const int tid = threadIdx.x;
  const int lane = tid & 63;
  const int m0 = blockIdx.y * 128, n0 = blockIdx.x * 128;
  const int wm = ((tid >> 6) >> 1) * 64, wn = ((tid >> 6) & 1) * 64;
  f32x4 acc[4][4];
#pragma unroll
  for (int i = 0; i < 4; ++i)
#pragma unroll
    for (int j = 0; j < 4; ++j) acc[i][j] = (f32x4)(0.f);
  // Pre-swizzled staging source coords: linear dest chunk (tid+256s)*16
  // holds logical (row = tid>>3 + 32s, col16 = (tid&7) ^ ((tid>>3)&7)).
  const int srow = tid >> 3;                         // + 32*s per pass
  const int scol = (((tid & 7) ^ ((tid >> 3) & 7)) << 3);  // bf16 elems
  const int lr = lane & 15, lg = lane >> 4;
  for (int k0 = 0; k0 < K; k0 += 64) {
    __syncthreads();
#pragma unroll
    for (int s = 0; s < 4; ++s)
      gload16(A + (size_t)(m0 + srow + 32 * s) * K + k0 + scol,
              sA + (tid + 256 * s) * 16);
#pragma unroll
    for (int s = 0; s < 4; ++s)
      gload16(Bt + (size_t)(n0 + srow + 32 * s) * K + k0 + scol,
              sB + (tid + 256 * s) * 16);
    __syncthreads();
#pragma unroll
    for (int kk = 0; kk < 64; kk += 32) {
      bf16x8 af[4], bfr[4];
#pragma unroll
      for (int i = 0; i < 4; ++i)
        af[i] = *(const bf16x8*)(sA + TSWZ(wm + i * 16 + lr, (kk + lg * 8) * 2));
#pragma unroll
      for (int j = 0; j < 4; ++j)
        bfr[j] = *(const bf16x8*)(sB + TSWZ(wn + j * 16 + lr, (kk + lg * 8) * 2));
#pragma unroll
      for (int i = 0; i < 4; ++i)
#pragma unroll
        for (int j = 0; j < 4; ++j)
          acc[i][j] = __builtin_amdgcn_mfma_f32_16x16x32_bf16(af[i], bfr[j], acc[i][j], 0, 0, 0);
    }
  }
  const int er = (lane >> 4) * 4, ec = lane & 15;
#pragma unroll
  for (int i = 0; i < 4; ++i) {
#pragma unroll
    for (int j = 0; j < 4; ++j) {
      int row = m0 + wm + i * 16 + er;
      int col = n0 + wn + j * 16 + ec;
#pragma unroll
      for (int r = 0; r < 4; ++r) {
        float v = acc[i][j][r];
        if constexpr (sizeof(OutT) == 2)
          C[(size_t)(row + r) * N + col] = __float2bfloat16(v);
        else
          C[(size_t)(row + r) * N + col] = v;
      }
    }
  }
}

// ---------------------------------------------------------------------------
// gemm_augu: z-muxed 128x128-tile GEMM over K=128.
//   z=0: a = ad@Wau; fused logsig -> per-64-chunk cumsum -> gc, glast
//   z=1: gd@Wgu -> gatef bf16.
// ---------------------------------------------------------------------------
__global__ __launch_bounds__(256) void gemm_augu(
    const __hip_bfloat16* __restrict__ ad, const __hip_bfloat16* __restrict__ gd,
    const __hip_bfloat16* __restrict__ Wau, const __hip_bfloat16* __restrict__ Wgu,
    float* __restrict__ gc, float* __restrict__ glast,
    __hip_bfloat16* __restrict__ gatef) {
  constexpr int N = 1024, K = 128;
  __shared__ alignas(16) char smraw[128 * 132 * 4];
  __hip_bfloat16* sA = (__hip_bfloat16*)smraw;
  __hip_bfloat16* sB = (__hip_bfloat16*)(smraw + 8192);
  float (*scan)[132] = (float(*)[132])smraw;

  const int z = blockIdx.z;
  const __hip_bfloat16* A = z ? gd : ad;
  const __hip_bfloat16* Bt = z ? Wgu : Wau;
  const int tid = threadIdx.x;
  const int lane = tid & 63;
  const int m0 = blockIdx.y * 128, n0 = blockIdx.x * 128;
  const int wm = ((tid >> 6) >> 1) * 64, wn = ((tid >> 6) & 1) * 64;
  f32x4 acc[4][4];
#pragma unroll
  for (int i = 0; i < 4; ++i)
#pragma unroll
    for (int j = 0; j < 4; ++j) acc[i][j] = (f32x4)(0.f);
  const int f0 = tid, f1 = tid + 256;
  const int r0 = f0 >> 2, c0 = (f0 & 3) * 8;
  const int r1 = f1 >> 2, c1 = (f1 & 3) * 8;
  const size_t aoff0 = (size_t)(m0 + r0) * K + c0;
  const size_t aoff1 = (size_t)(m0 + r1) * K + c1;
  const size_t boff0 = (size_t)(n0 + r0) * K + c0;
  const size_t boff1 = (size_t)(n0 + r1) * K + c1;
  const int lr = lane & 15, lk = (lane >> 4) * 8;
#pragma unroll
  for (int k0 = 0; k0 < K; k0 += 32) {
    __syncthreads();
    gload16(A + aoff0 + k0, &sA[f0 * 8]);
    gload16(A + aoff1 + k0, &sA[f1 * 8]);
    gload16(Bt + boff0 + k0, &sB[f0 * 8]);
    gload16(Bt + boff1 + k0, &sB[f1 * 8]);
    __syncthreads();
    bf16x8 af[4], bfr[4];
#pragma unroll
    for (int i = 0; i < 4; ++i)
      af[i] = *(const bf16x8*)&sA[(wm + i * 16 + lr) * 32 + lk];
#pragma unroll
    for (int j = 0; j < 4; ++j)
      bfr[j] = *(const bf16x8*)&sB[(wn + j * 16 + lr) * 32 + lk];
#pragma unroll
    for (int i = 0; i < 4; ++i)
#pragma unroll
      for (int j = 0; j < 4; ++j)
        acc[i][j] = __builtin_amdgcn_mfma_f32_16x16x32_bf16(af[i], bfr[j], acc[i][j], 0, 0, 0);
  }
  const int er = (lane >> 4) * 4, ec = lane & 15;
  if (z == 1) {
#pragma unroll
    for (int i = 0; i < 4; ++i)
#pragma unroll
      for (int j = 0; j < 4; ++j) {
        int row = m0 + wm + i * 16 + er;
        int col = n0 + wn + j * 16 + ec;
#pragma unroll
        for (int r = 0; r < 4; ++r)
          gatef[(size_t)(row + r) * N + col] = __float2bfloat16(acc[i][j][r]);
      }
    return;
  }
  __syncthreads();
#pragma unroll
  for (int i = 0; i < 4; ++i)
#pragma unroll
    for (int j = 0; j < 4; ++j) {
      int rowL = wm + i * 16 + er;
      int colL = wn + j * 16 + ec;
#pragma unroll
      for (int r = 0; r < 4; ++r) {
        float a = acc[i][j][r];
        float s = fmaxf(1.f / (1.f + __expf(-a)), 1e-6f);
        scan[rowL + r][colL] = __logf(s);
      }
    }
  __syncthreads();
  {
    const int d = tid & 127, c2 = tid >> 7;
    const int h = blockIdx.x;
    const int b = m0 >> 11, tb = m0 & 2047;
    const int bh = b * H_ + h;
    float run = 0.f;
    const size_t gbase = ((size_t)bh * T_ + tb + c2 * 64) * 128 + d;
    for (int r = 0; r < 64; ++r) {
      run += scan[c2 * 64 + r][d];
      gc[gbase + (size_t)r * 128] = run;
    }
    glast[((size_t)(bh * NT_ + (tb >> 6) + c2)) * 128 + d] = run;
  }
}

// ---------------------------------------------------------------------------
// prep: merged cvt_bf (x -> xb) + weight transpose-conversions.
// ---------------------------------------------------------------------------
__global__ __launch_bounds__(256) void prep(
    const float* __restrict__ x, const float* __restrict__ Wq,
    const float* __restrict__ Wk, const float* __restrict__ Wv,
    const float* __restrict__ Wad, const float* __restrict__ Wgd,
    const float* __restrict__ Wau, const float* __restrict__ Wgu,
    const float* __restrict__ Wo, __hip_bfloat16* __restrict__ xb,
    __hip_bfloat16* __restrict__ Wt_qkv, __hip_bfloat16* __restrict__ Wt_dg,
    __hip_bfloat16* __restrict__ Wt_aug, __hip_bfloat16* __restrict__ Wt_o) {
  __shared__ float tile[64][33];
  int bid = blockIdx.x;
  const int tid = threadIdx.x;
  if (bid < 8192) {
    size_t i = ((size_t)bid * 256 + tid) * 4;
    float4 v = *(const float4*)(x + i);
    union { __hip_bfloat16 hx[4]; uint2 u2; } pk_;
    pk_.hx[0] = __float2bfloat16(v.x);
    pk_.hx[1] = __float2bfloat16(v.y);
    pk_.hx[2] = __float2bfloat16(v.z);
    pk_.hx[3] = __float2bfloat16(v.w);
    *(uint2*)(xb + i) = pk_.u2;
    return;
  }
  bid -= 8192;
  const float* W; __hip_bfloat16* dst; int K, N, bx, by;
  if (bid < 3072) {
    int z = bid / 1024, r = bid % 1024;
    W = (z == 0) ? Wq : (z == 1) ? Wk : Wv;
    dst = Wt_qkv + (size_t)z * C_ * D_;
    K = D_; N = C_; bx = r & 31; by = r >> 5;
  } else if (bid < 3072 + 256) {
    int b2 = bid - 3072;
    int z = b2 >> 7, r = b2 & 127;
    W = z ? Wgd : Wad;
    dst = Wt_dg + (size_t)z * HD_ * D_;
    K = D_; N = HD_; bx = r & 3; by = r >> 2;
  } else if (bid < 3072 + 256 + 128) {
    int b2 = bid - 3328;
    int z = b2 >> 6, r = b2 & 63;
    W = z ? Wgu : Wau;
    dst = Wt_aug + (size_t)z * C_ * HD_;
    K = HD_; N = C_; bx = r & 31; by = r >> 5;
  } else {
    int b2 = bid - 3456;
    W = Wo; dst = Wt_o;
    K = C_; N = D_; bx = b2 & 63; by = b2 >> 6;
  }
  const int kb = by * 64, nb = bx * 32;
#pragma unroll
  for (int p = 0; p < 2; ++p) {
    const int kk = (tid >> 3) + p * 32;
    const int c4 = (tid & 7) * 4;
    float4 v = *(const float4*)(W + (size_t)(kb + kk) * N + nb + c4);
    tile[kk][c4 + 0] = v.x;
    tile[kk][c4 + 1] = v.y;
    tile[kk][c4 + 2] = v.z;
    tile[kk][c4 + 3] = v.w;
  }
  __syncthreads();
  {
    const int nn = tid >> 3, kk8 = (tid & 7) * 8;
    union { __hip_bfloat16 hx[8]; uint4 u4; } pk_;
#pragma unroll
    for (int e = 0; e < 8; ++e) pk_.hx[e] = __float2bfloat16(tile[kk8 + e][nn]);
    *(uint4*)(dst + (size_t)(nb + nn) * K + kb + kk8) = pk_.u4;
  }
}

// ---------------------------------------------------------------------------
// chunk_mid (fused conv + pairdot + solve + ppre), 512 threads, 512 blocks.
// ---------------------------------------------------------------------------
__global__ __launch_bounds__(512) void chunk_mid(
    const __hip_bfloat16* __restrict__ pre, const float* __restrict__ gc,
    const float* __restrict__ cqw, const float* __restrict__ cqb,
    const float* __restrict__ ckw, const float* __restrict__ ckb,
    const float* __restrict__ cvw, const float* __restrict__ cvb,
    __hip_bfloat16* __restrict__ qg, __hip_bfloat16* __restrict__ Aq,
    __hip_bfloat16* __restrict__ w_bf, __hip_bfloat16* __restrict__ u_bf,
    __hip_bfloat16* __restrict__ PT_bf) {
  __shared__ alignas(16) char smc[66560];
  char* kpL = smc;                                  // 16 KB (dead after P2a)
  char* vbL = smc + 16384;                          // 16 KB (dead after P2a)
  char* kmL = smc + 32768;                          // 16 KB (live thru P2b)
  float (*A_T)[68] = (float(*)[68])(smc + 49152);   // 17,408 B
  char* soluT = kpL;                                // bf16 [128 vd][64 i], swz
  char* kmT   = vbL;                                // bf16 [128 kd][64 i], swz

  const int tid = threadIdx.x;
  const int bhn = blockIdx.x;
  const int bh = bhn >> 5, n = bhn & 31;
  const int b = bh >> 3, h = bh & 7;
  const size_t gbase = ((size_t)bh * T_ + (size_t)n * BT_) * HD_;
  const int wv = tid >> 6, lane = tid & 63;
  const int lr = lane & 15, lg = lane >> 4;

  // ---- P0: fused conv (8 rows per wave, 2 channels per lane) ----
  {
    const int d0 = lane * 2;
    const int c0 = h * HD_ + d0;
    float qw[2][4], kw[2][4], vw[2][4], qb2[2], kb2[2], vb2[2];
#pragma unroll
    for (int e = 0; e < 2; ++e) {
      const int c = c0 + e;
#pragma unroll
      for (int j = 0; j < 4; ++j) {
        qw[e][j] = cqw[c * 4 + j];
        kw[e][j] = ckw[c * 4 + j];
        vw[e][j] = cvw[c * 4 + j];
      }
      qb2[e] = cqb[c]; kb2[e] = ckb[c]; vb2[e] = cvb[c];
    }
    const int tw0 = n * 64 + wv * 8;
    const size_t prow0 = ((size_t)b * T_ + tw0) * (3 * C_) + c0;
    float xm[3][3][2];
#pragma unroll
    for (int a = 0; a < 3; ++a)
#pragma unroll
      for (int g2 = 0; g2 < 3; ++g2) { xm[a][g2][0] = 0.f; xm[a][g2][1] = 0.f; }
#pragma unroll
    for (int g2 = 1; g2 <= 3; ++g2) {
      if (tw0 - g2 >= 0) {
        const __hip_bfloat16* pr = pre + (prow0 - (size_t)g2 * (3 * C_));
#pragma unroll
        for (int a = 0; a < 3; ++a) {
          uint u = *(const uint*)(pr + a * C_);
          xm[a][g2 - 1][0] = __bfloat162float(((const __hip_bfloat16*)&u)[0]);
          xm[a][g2 - 1][1] = __bfloat162float(((const __hip_bfloat16*)&u)[1]);
        }
      }
    }
#pragma unroll
    for (int i = 0; i < 8; ++i) {
      const int t = tw0 + i;
      const __hip_bfloat16* pr = pre + (prow0 + (size_t)i * (3 * C_));
      float x0[3][2];
#pragma unroll
      for (int a = 0; a < 3; ++a) {
        uint u = *(const uint*)(pr + a * C_);
        x0[a][0] = __bfloat162float(((const __hip_bfloat16*)&u)[0]);
        x0[a][1] = __bfloat162float(((const __hip_bfloat16*)&u)[1]);
      }
      float aq[2], ak[2], av[2];
#pragma unroll
      for (int e = 0; e < 2; ++e) {
        aq[e] = qb2[e] + qw[e][3] * x0[0][e];
        if (t > 0) aq[e] += qw[e][2] * xm[0][0][e];
        if (t > 1) aq[e] += qw[e][1] * xm[0][1][e];
        if (t > 2) aq[e] += qw[e][0] * xm[0][2][e];
        ak[e] = kb2[e] + kw[e][3] * x0[1][e];
        if (t > 0) ak[e] += kw[e][2] * xm[1][0][e];
        if (t > 1) ak[e] += kw[e][1] * xm[1][1][e];
        if (t > 2) ak[e] += kw[e][0] * xm[1][2][e];
        av[e] = vb2[e] + vw[e][3] * x0[2][e];
        if (t > 0) av[e] += vw[e][2] * xm[2][0][e];
        if (t > 1) av[e] += vw[e][1] * xm[2][1][e];
        if (t > 2) av[e] += vw[e][0] * xm[2][2][e];
      }
#pragma unroll
      for (int a = 0; a < 3; ++a) {
#pragma unroll
        for (int e = 0; e < 2; ++e) {
          xm[a][2][e] = xm[a][1][e];
          xm[a][1][e] = xm[a][0][e];
          xm[a][0][e] = x0[a][e];
        }
      }
      float ssq = aq[0] * aq[0] + aq[1] * aq[1];
      float ssk = ak[0] * ak[0] + ak[1] * ak[1];
#pragma unroll
      for (int o = 1; o < 64; o <<= 1) {
        ssq += __shfl_xor(ssq, o);
        ssk += __shfl_xor(ssk, o);
      }
      const float nq = fmaxf(sqrtf(ssq), 1e-12f);
      const float nk = fmaxf(sqrtf(ssk), 1e-12f);
      const int row = wv * 8 + i;
      const size_t oi = gbase + (size_t)row * 128 + d0;
      const float2 gv = *(const float2*)(gc + oi);
      union { __hip_bfloat16 hx[2]; uint u; } oq, okp, okm, ov;
#pragma unroll
      for (int e = 0; e < 2; ++e) {
        const float g = (e == 0) ? gv.x : gv.y;
        const float eg = __expf(g), emg = __expf(-g);
        oq.hx[e]  = __float2bfloat16(aq[e] / nq * eg);
        const float kn = ak[e] / nk;
        okp.hx[e] = __float2bfloat16(kn * eg);
        okm.hx[e] = __float2bfloat16(kn * emg);
        ov.hx[e]  = __float2bfloat16(av[e] * (1.f / (1.f + __expf(-av[e]))));
      }
      *(uint*)(qg + oi) = oq.u;
      *(uint*)(kpL + SWZ(row, d0 * 2)) = okp.u;
      *(uint*)(kmL + SWZ(row, d0 * 2)) = okm.u;
      *(uint*)(vbL + SWZ(row, d0 * 2)) = ov.u;
    }
  }
  __syncthreads();

  // ---- P1: MFMA pair products (4 waves/product, 16-row slices) ----
  {
    const int prod = wv >> 2, rh = wv & 3;
    f32x4 acc[4];
#pragma unroll
    for (int j = 0; j < 4; ++j) acc[j] = (f32x4)(0.f);
#pragma unroll
    for (int k0 = 0; k0 < 128; k0 += 32) {
      bf16x8 af, bfr[4];
      const int ar = rh * 16 + lr;
      if (prod == 0)
        af = *(const bf16x8*)(kmL + SWZ(ar, (k0 + lg * 8) * 2));
      else
        af = *(const bf16x8*)(qg + gbase + (size_t)ar * 128 + k0 + lg * 8);
#pragma unroll
      for (int j = 0; j < 4; ++j) {
        const int br = j * 16 + lr;
        bfr[j] = (prod == 0)
          ? *(const bf16x8*)(kpL + SWZ(br, (k0 + lg * 8) * 2))
          : *(const bf16x8*)(kmL + SWZ(br, (k0 + lg * 8) * 2));
      }
#pragma unroll
      for (int j = 0; j < 4; ++j)
        acc[j] = __builtin_amdgcn_mfma_f32_16x16x32_bf16(af, bfr[j], acc[j], 0, 0, 0);
    }
    if (prod == 0) {
#pragma unroll
      for (int j = 0; j < 4; ++j) {
        int row0 = rh * 16 + lg * 4;
        int col = j * 16 + lr;
        *(float4*)&A_T[col][row0] =
            make_float4(acc[j][0], acc[j][1], acc[j][2], acc[j][3]);
      }
    } else {
      __hip_bfloat16* dst = Aq + (size_t)bhn * 4096;
#pragma unroll
      for (int j = 0; j < 4; ++j)
#pragma unroll
        for (int r = 0; r < 4; ++r) {
          int row = rh * 16 + lg * 4 + r;
          int col = j * 16 + lr;
          float v = (col <= row) ? acc[j][r] : 0.f;
          dst[row * 64 + col] = __float2bfloat16(v);
        }
    }
  }
  __syncthreads();

  // ---- P2a: rhs from LDS into registers (kp for w-cols, vb for u-cols) ----
  float s[64];
  const int col = tid & 127;
  if (tid < 256) {
    const char* rhsL = (tid < 128) ? kpL : vbL;
#pragma unroll
    for (int i = 0; i < 64; ++i)
      s[i] = __bfloat162float(*(const __hip_bfloat16*)(rhsL + SWZ(i, col * 2)));
  }
  __syncthreads();   // kpL/vbL now dead -> soluT/kmT may overwrite

  // ---- P2b: solve (threads 0-255) || kmL->kmT transpose (threads 256-511) ----
  if (tid < 256) {
#pragma unroll
    for (int ib = 0; ib < 64; ib += 4) {
      const float s0 = s[ib];
      const float s1 = fmaf(-A_T[ib][ib + 1], s0, s[ib + 1]);
      const float s2 = fmaf(-A_T[ib + 1][ib + 2], s1,
                       fmaf(-A_T[ib][ib + 2], s0, s[ib + 2]));
      const float s3 = fmaf(-A_T[ib + 2][ib + 3], s2,
                       fmaf(-A_T[ib + 1][ib + 3], s1,
                       fmaf(-A_T[ib][ib + 3], s0, s[ib + 3])));
      s[ib + 1] = s1; s[ib + 2] = s2; s[ib + 3] = s3;
#pragma unroll
      for (int j4 = ib + 4; j4 < 64; j4 += 4) {
        float4 a0 = *(const float4*)&A_T[ib][j4];
        float4 a1 = *(const float4*)&A_T[ib + 1][j4];
        float4 a2 = *(const float4*)&A_T[ib + 2][j4];
        float4 a3 = *(const float4*)&A_T[ib + 3][j4];
        s[j4]     = fmaf(-a3.x, s3, fmaf(-a2.x, s2, fmaf(-a1.x, s1, fmaf(-a0.x, s0, s[j4]))));
        s[j4 + 1] = fmaf(-a3.y, s3, fmaf(-a2.y, s2, fmaf(-a1.y, s1, fmaf(-a0.y, s0, s[j4 + 1]))));
        s[j4 + 2] = fmaf(-a3.z, s3, fmaf(-a2.z, s2, fmaf(-a1.z, s1, fmaf(-a0.z, s0, s[j4 + 2]))));
        s[j4 + 3] = fmaf(-a3.w, s3, fmaf(-a2.w, s2, fmaf(-a1.w, s1, fmaf(-a0.w, s0, s[j4 + 3]))));
      }
    }
    if (tid < 128) {
#pragma unroll
      for (int i = 0; i < 64; ++i)
        w_bf[gbase + (size_t)i * 128 + col] = __float2bfloat16(s[i]);
    } else {
#pragma unroll
      for (int i = 0; i < 64; ++i)
        u_bf[gbase + (size_t)i * 128 + col] = __float2bfloat16(s[i]);
#pragma unroll
      for (int c8 = 0; c8 < 8; ++c8) {
        union { __hip_bfloat16 hx[8]; uint4 u4; } pk2;
#pragma unroll
        for (int e = 0; e < 8; ++e) pk2.hx[e] = __float2bfloat16(s[c8 * 8 + e]);
        *(uint4*)(soluT + TSWZ(col, c8 * 16)) = pk2.u4;
      }
    }
  } else {
    const int t2 = tid - 256;
    const int d = (t2 & 63) * 2;
    const int i0 = (t2 >> 6) * 16;
    __hip_bfloat16 rlo[16], rhi[16];
#pragma unroll
    for (int ii = 0; ii < 16; ++ii) {
      uint u = *(const uint*)(kmL + SWZ(i0 + ii, d * 2));
      rlo[ii] = ((const __hip_bfloat16*)&u)[0];
      rhi[ii] = ((const __hip_bfloat16*)&u)[1];
    }
    *(uint4*)(kmT + TSWZ(d, i0 * 2))          = *(uint4*)&rlo[0];
    *(uint4*)(kmT + TSWZ(d, i0 * 2 + 16))     = *(uint4*)&rlo[8];
    *(uint4*)(kmT + TSWZ(d + 1, i0 * 2))      = *(uint4*)&rhi[0];
    *(uint4*)(kmT + TSWZ(d + 1, i0 * 2 + 16)) = *(uint4*)&rhi[8];
  }
  __syncthreads();

  // ---- P3: PT[vd][kd] = sum_i soluT[vd][i]*kmT[kd][i] via MFMA ----
  {
    f32x4 acc[8];
#pragma unroll
    for (int j = 0; j < 8; ++j) acc[j] = (f32x4)(0.f);
    const int vd = wv * 16 + lr;
#pragma unroll
    for (int k0 = 0; k0 < 64; k0 += 32) {
      bf16x8 af = *(const bf16x8*)(soluT + TSWZ(vd, (k0 + lg * 8) * 2));
#pragma unroll
      for (int j = 0; j < 8; ++j) {
        const int kd = j * 16 + lr;
        bf16x8 bf_ = *(const bf16x8*)(kmT + TSWZ(kd, (k0 + lg * 8) * 2));
        acc[j] = __builtin_amdgcn_mfma_f32_16x16x32_bf16(af, bf_, acc[j], 0, 0, 0);
      }
    }
    __hip_bfloat16* dst = PT_bf + (size_t)bhn * 16384;
#pragma unroll
    for (int j = 0; j < 8; ++j)
#pragma unroll
      for (int r = 0; r < 4; ++r) {
        const int vdr = wv * 16 + lg * 4 + r;
        const int kd = j * 16 + lr;
        dst[vdr * 128 + kd] = __float2bfloat16(acc[j][r]);
      }
  }
}

// ---------------------------------------------------------------------------
// scan over chunks on PT layout (bf16 in, f32 accumulate), software-pipelined.
// ---------------------------------------------------------------------------
__global__ __launch_bounds__(128) void scan_pt(
    const __hip_bfloat16* __restrict__ PT_bf, const float* __restrict__ glast,
    __hip_bfloat16* __restrict__ STg, float* __restrict__ Sout) {
  int vd = blockIdx.x & 127;
  int bh = blockIdx.x >> 7;
  int kd = threadIdx.x;
  const size_t base = (((size_t)bh * NT_) * HD_ + vd) * HD_ + kd;
  const size_t gstep = (size_t)HD_ * HD_;
  const float* glp = glast + (size_t)bh * NT_ * 128 + kd;
  float s = 0.f;
  float p = __bfloat162float(PT_bf[base]);
  float gl = glp[0];
#pragma unroll 4
  for (int n = 0; n < NT_ - 1; ++n) {
    const float pn = __bfloat162float(PT_bf[base + (size_t)(n + 1) * gstep]);
    const float gn = glp[(size_t)(n + 1) * 128];
    STg[base + (size_t)n * gstep] = __float2bfloat16(s);
    s = (s + p) * __expf(gl);
    p = pn; gl = gn;
  }
  STg[base + (size_t)(NT_ - 1) * gstep] = __float2bfloat16(s);
  s = (s + p) * __expf(gl);
  Sout[((size_t)bh * HD_ + kd) * HD_ + vd] = s;
}

// ---------------------------------------------------------------------------
// chunk_tail (8-wave): waves own (row-half x col-quarter) 32x32 sub-tiles.
// ---------------------------------------------------------------------------
__global__ __launch_bounds__(512) void chunk_tail(
    const __hip_bfloat16* __restrict__ qg_bf, const __hip_bfloat16* __restrict__ w_bf,
    const __hip_bfloat16* __restrict__ u_bf, const __hip_bfloat16* __restrict__ Aq_bf,
    const __hip_bfloat16* __restrict__ STg, const __hip_bfloat16* __restrict__ gatef,
    const float* __restrict__ normw, __hip_bfloat16* __restrict__ o2b) {
  constexpr int XTS = 72;
  __shared__ __hip_bfloat16 XT[128 * XTS];
  __shared__ float red[64][4];
  __shared__ __hip_bfloat16 uS[64 * 128];   // async-staged u chunk (16 KB)
  const int tid = threadIdx.x;
  const int bhn = blockIdx.x;
  const int bh = bhn >> 5, n = bhn & 31;
  const int b = bh >> 3, h = bh & 7;
  const int t0 = n * 64, hoff = h * 128;
  const size_t gbase = ((size_t)bh * T_ + t0) * 128;
  const __hip_bfloat16* Sg = STg + (size_t)bhn * 16384;

  {
    const char* src = (const char*)(u_bf + gbase);
#pragma unroll
    for (int s = 0; s < 2; ++s)
      gload16(src + s * 8192 + tid * 16, ((char*)uS) + s * 8192 + tid * 16);
  }

  const int wv = tid >> 6, lane = tid & 63;
  const int lr = lane & 15, lg = lane >> 4;
  const int rowh = wv >> 2, colq = wv & 3;
  f32x4 accX[2][2], accO[2][2];
#pragma unroll
  for (int i = 0; i < 2; ++i)
#pragma unroll
    for (int j = 0; j < 2; ++j) { accX[i][j] = (f32x4)(0.f); accO[i][j] = (f32x4)(0.f); }

  const __hip_bfloat16* wrow = w_bf + gbase;
  const __hip_bfloat16* qrow = qg_bf + gbase;
#pragma unroll
  for (int k0 = 0; k0 < 128; k0 += 32) {
    bf16x8 aW[2], aQ[2], bS[2];
#pragma unroll
    for (int i = 0; i < 2; ++i) {
      aW[i] = *(const bf16x8*)(wrow + (size_t)(rowh * 32 + i * 16 + lr) * 128 + k0 + lg * 8);
      aQ[i] = *(const bf16x8*)(qrow + (size_t)(rowh * 32 + i * 16 + lr) * 128 + k0 + lg * 8);
    }
#pragma unroll
    for (int j = 0; j < 2; ++j)
      bS[j] = *(const bf16x8*)(Sg + (size_t)(colq * 32 + j * 16 + lr) * 128 + k0 + lg * 8);
#pragma unroll
    for (int i = 0; i < 2; ++i)
#pragma unroll
      for (int j = 0; j < 2; ++j) {
        accX[i][j] = __builtin_amdgcn_mfma_f32_16x16x32_bf16(aW[i], bS[j], accX[i][j], 0, 0, 0);
        accO[i][j] = __builtin_amdgcn_mfma_f32_16x16x32_bf16(aQ[i], bS[j], accO[i][j], 0, 0, 0);
      }
  }

  asm volatile("s_waitcnt vmcnt(0)" ::: "memory");
  __builtin_amdgcn_s_barrier();

#pragma unroll
  for (int i = 0; i < 2; ++i)
#pragma unroll
    for (int j = 0; j < 2; ++j) {
      int row0 = rowh * 32 + i * 16 + lg * 4;
      int col = colq * 32 + j * 16 + lr;
      union { __hip_bfloat16 hx[4]; uint2 u2; } xv;
#pragma unroll
      for (int r = 0; r < 4; ++r) {
        float uu = __bfloat162float(uS[(row0 + r) * 128 + col]);
        xv.hx[r] = __float2bfloat16(uu - accX[i][j][r]);
      }
      *(uint2*)&XT[col * XTS + row0] = xv.u2;
    }
  __syncthreads();

  const __hip_bfloat16* aqb = Aq_bf + (size_t)bhn * 4096;
#pragma unroll
  for (int k0 = 0; k0 < 64; k0 += 32) {
    bf16x8 aA[2], bX[2];
#pragma unroll
    for (int i = 0; i < 2; ++i)
      aA[i] = *(const bf16x8*)(aqb + (size_t)(rowh * 32 + i * 16 + lr) * 64 + k0 + lg * 8);
#pragma unroll
    for (int j = 0; j < 2; ++j)
      bX[j] = *(const bf16x8*)&XT[(colq * 32 + j * 16 + lr) * XTS + k0 + lg * 8];
#pragma unroll
    for (int i = 0; i < 2; ++i)
#pragma unroll
      for (int j = 0; j < 2; ++j)
        accO[i][j] = __builtin_amdgcn_mfma_f32_16x16x32_bf16(aA[i], bX[j], accO[i][j], 0, 0, 0);
  }

#pragma unroll
  for (int i = 0; i < 2; ++i)
#pragma unroll
    for (int r = 0; r < 4; ++r) {
      int row = rowh * 32 + i * 16 + lg * 4 + r;
      float o0 = accO[i][0][r], o1 = accO[i][1][r];
      float ss = o0 * o0 + o1 * o1;
#pragma unroll
      for (int o = 1; o < 16; o <<= 1) ss += __shfl_xor(ss, o);
      if (lr == 0) red[row][colq] = ss;
    }
  __syncthreads();
  float nw0 = normw[colq * 32 + lr];
  float nw1 = normw[colq * 32 + 16 + lr];
#pragma unroll
  for (int i = 0; i < 2; ++i)
#pragma unroll
    for (int r = 0; r < 4; ++r) {
      int row = rowh * 32 + i * 16 + lg * 4 + r;
      float tot = red[row][0] + red[row][1] + red[row][2] + red[row][3];
      float rms = rsqrtf(tot * (1.f / 128.f) + EPS_RMS);
      size_t orow = (size_t)(b * T_ + t0 + row) * C_ + hoff;
      int c0 = colq * 32 + lr, c1 = c0 + 16;
      float g0 = __bfloat162float(gatef[orow + c0]);
      float g1 = __bfloat162float(gatef[orow + c1]);
      float s0 = 1.f / (1.f + __expf(-g0));
      float s1 = 1.f / (1.f + __expf(-g1));
      o2b[orow + c0] = __float2bfloat16(accO[i][0][r] * rms * nw0 * s0);
      o2b[orow + c1] = __float2bfloat16(accO[i][1][r] * rms * nw1 * s1);
    }
}

// ---------------------------------------------------------------------------
extern "C" void kernel_launch(void* const* d_in, const int* in_sizes, int n_in,
                              void* d_out, int out_size, void* d_ws, size_t ws_size,
                              hipStream_t stream) {
  (void)in_sizes; (void)n_in; (void)out_size;
  const float* x    = (const float*)d_in[0];
  const float* Wq   = (const float*)d_in[1];
  const float* Wk   = (const float*)d_in[2];
  const float* Wv   = (const float*)d_in[3];
  const float* cqw  = (const float*)d_in[4];
  const float* cqb  = (const float*)d_in[5];
  const float* ckw  = (const float*)d_in[6];
  const float* ckb  = (const float*)d_in[7];
  const float* cvw  = (const float*)d_in[8];
  const float* cvb  = (const float*)d_in[9];
  const float* Wad  = (const float*)d_in[10];
  const float* Wau  = (const float*)d_in[11];
  // d_in[12] = Wb : dead code in reference
  const float* Wgd  = (const float*)d_in[13];
  const float* Wgu  = (const float*)d_in[14];
  const float* normw= (const float*)d_in[15];
  const float* Wo   = (const float*)d_in[16];

  float* outp = (float*)d_out;
  float* Sout = outp + (size_t)M_ * D_;

  const size_t SZ = (size_t)M_ * C_;  // 4,194,304 f32 units

  float* ws = (float*)d_ws;
  __hip_bfloat16* pre_qkv = (__hip_bfloat16*)(ws);                 // 1.5 SZ
  float* a_full = ws + 3 * SZ / 2;                                  // 1 SZ (o2b alias region)
  __hip_bfloat16* gatef = (__hip_bfloat16*)(ws + 5 * SZ / 2);       // 0.5 SZ
  float* gc_g = ws + 3 * SZ;                                        // 1 SZ
  __hip_bfloat16* qg_bf = (__hip_bfloat16*)(ws + 4 * SZ);           // 0.5 SZ
  __hip_bfloat16* w_bf  = (__hip_bfloat16*)(ws + 6 * SZ);           // 0.5 SZ
  __hip_bfloat16* u_bf  = (__hip_bfloat16*)(ws + 13 * SZ / 2);      // 0.5 SZ
  __hip_bfloat16* Aq_bf = (__hip_bfloat16*)(ws + 7 * SZ);           // 0.25 SZ
  float* glast = ws + 29 * SZ / 4;                                  // 65536 units
  __hip_bfloat16* PT_bf = (__hip_bfloat16*)(ws + 15 * SZ / 2);      // 1 SZ
  __hip_bfloat16* STg   = (__hip_bfloat16*)(ws + 17 * SZ / 2);      // 1 SZ
  __hip_bfloat16* xb    = (__hip_bfloat16*)(ws + 19 * SZ / 2);      // 1 SZ
  __hip_bfloat16* Wt_qkv = (__hip_bfloat16*)(ws + 21 * SZ / 2);     // 0.75 SZ
  size_t off = 21 * SZ / 2 + 3 * SZ / 4;
  __hip_bfloat16* Wt_dg  = (__hip_bfloat16*)(ws + off); off += 262144;  // contiguous after Wt_qkv
  __hip_bfloat16* Wt_aug = (__hip_bfloat16*)(ws + off); off += 131072;
  __hip_bfloat16* Wt_o   = (__hip_bfloat16*)(ws + off); off += 1048576;
  __hip_bfloat16* ad_bf  = (__hip_bfloat16*)(ws + off); off += 262144;
  __hip_bfloat16* gd_bf  = (__hip_bfloat16*)(ws + off); off += 262144;
  if (ws_size < off * sizeof(float)) return;

  __hip_bfloat16* o2b = (__hip_bfloat16*)a_full;  // a_full region reused for o2b
  __hip_bfloat16* Wt_au = Wt_aug;
  __hip_bfloat16* Wt_gu = Wt_aug + (size_t)C_ * HD_;

  // Phase 0: all bf16 conversions in one launch (64x32 transpose tiles)
  prep<<<12672, 256, 0, stream>>>(x, Wq, Wk, Wv, Wad, Wgd, Wau, Wgu, Wo,
                                  xb, Wt_qkv, Wt_dg, Wt_aug, Wt_o);

  // Phase 1: qkv + dg projection in one 8-phase 256^2 launch
  gemm8p<<<208, 512, 0, stream>>>(xb, Wt_qkv, pre_qkv, ad_bf, gd_bf);
  // au/gu projection; z=0 fuses the logsig + per-chunk cumsum (gc, glast)
  gemm_augu<<<dim3(C_ / 128, M_ / 128, 2), 256, 0, stream>>>(
      ad_bf, gd_bf, Wt_au, Wt_gu, gc_g, glast, gatef);

  // Phase 2+3: fused conv + pairdot + solve + ppre, then state scan
  chunk_mid<<<B_ * H_ * NT_, 512, 0, stream>>>(pre_qkv, gc_g, cqw, cqb, ckw, ckb,
                                               cvw, cvb, qg_bf, Aq_bf, w_bf,
                                               u_bf, PT_bf);
  scan_pt<<<B_ * H_ * HD_, 128, 0, stream>>>(PT_bf, glast, STg, Sout);

  // Phase 4: fused output tail (8-wave) + projection (BK=64 swizzled)
  chunk_tail<<<B_ * H_ * NT_, 512, 0, stream>>>(qg_bf, w_bf, u_bf, Aq_bf, STg,
                                                gatef, normw, o2b);
  gemm_bf16k<float><<<dim3(D_ / 128, M_ / 128), 256, 0, stream>>>(o2b, Wt_o, outp, D_, C_);
}

// Round 13
// 322.171 us; speedup vs baseline: 1.4139x; 1.4139x over previous
//
#include <hip/hip_runtime.h>
#include <hip/hip_bf16.h>
#include <cstdint>
#include <cstddef>

// Problem constants
constexpr int B_  = 2;
constexpr int T_  = 2048;
constexpr int D_  = 2048;
constexpr int H_  = 8;
constexpr int HD_ = 128;
constexpr int C_  = 1024;   // H*HD
constexpr int BT_ = 64;
constexpr int NT_ = 32;     // T/BT
constexpr int M_  = 4096;   // B*T
constexpr float EPS_RMS = 1.1920929e-07f;

typedef __bf16 bf16x8 __attribute__((ext_vector_type(8)));
typedef float f32x4 __attribute__((ext_vector_type(4)));

typedef const __attribute__((address_space(1))) unsigned int* gptr_t;
typedef __attribute__((address_space(3))) unsigned int* lptr_t;

__device__ __forceinline__ void gload16(const void* g, void* l) {
  __builtin_amdgcn_global_load_lds((gptr_t)g, (lptr_t)l, 16, 0, 0);
}

// Swizzled byte offset into a [64][128] bf16 LDS tile (row stride 256 B).
#define SWZ(row, cbytes) ((((row) * 256) + (cbytes)) ^ (((row) & 7) << 4))
// Swizzled byte offset into a [*][64] bf16 LDS tile (row stride 128 B).
#define TSWZ(row, cbytes) ((((row) * 128) + (cbytes)) ^ (((row) & 7) << 4))

// ---------------------------------------------------------------------------
// gemm8p: 256x256-tile, BK=64, 8-wave, 8-phase counted-vmcnt GEMM.
// (round-2 verified form)
// ---------------------------------------------------------------------------

#define LD_A(base, mq, dst) do { \
    _Pragma("unroll") for (int i_ = 0; i_ < 4; ++i_) \
      _Pragma("unroll") for (int k_ = 0; k_ < 2; ++k_) \
        dst[i_][k_] = *(const bf16x8*)((base) + (mq) * 8192 + i_ * 2048 + k_ * 1024); \
  } while (0)

#define LD_B(base, nq, dst) do { \
    _Pragma("unroll") for (int j_ = 0; j_ < 2; ++j_) \
      _Pragma("unroll") for (int k_ = 0; k_ < 2; ++k_) \
        dst[j_][k_] = *(const bf16x8*)((base) + (nq) * 4096 + j_ * 2048 + k_ * 1024); \
  } while (0)

#define MM_Q(afr, bfr, mq, nq) do { \
    _Pragma("unroll") for (int i_ = 0; i_ < 4; ++i_) \
      _Pragma("unroll") for (int j_ = 0; j_ < 2; ++j_) \
        _Pragma("unroll") for (int k_ = 0; k_ < 2; ++k_) \
          acc[(mq) * 4 + i_][(nq) * 2 + j_] = __builtin_amdgcn_mfma_f32_16x16x32_bf16( \
              afr[i_][k_], bfr[j_][k_], acc[(mq) * 4 + i_][(nq) * 2 + j_], 0, 0, 0); \
  } while (0)

#define STAGE(src, grow0, kc, loff) do { \
    gload16((src) + (size_t)((grow0) + sr0) * 2048 + (kc) + sc0, smem + (loff) + tid * 16); \
    gload16((src) + (size_t)((grow0) + sr1) * 2048 + (kc) + sc1, smem + (loff) + 8192 + tid * 16); \
  } while (0)

#define PH_SYNC_PRE do { \
    __builtin_amdgcn_s_barrier(); \
    asm volatile("s_waitcnt lgkmcnt(0)" ::: "memory"); \
    __builtin_amdgcn_sched_barrier(0); \
    __builtin_amdgcn_s_setprio(1); \
  } while (0)

#define PH_SYNC_POST do { \
    __builtin_amdgcn_s_setprio(0); \
    __builtin_amdgcn_sched_barrier(0); \
    __builtin_amdgcn_s_barrier(); \
  } while (0)

#define PH_SYNC_POST_VM4 do { \
    __builtin_amdgcn_s_setprio(0); \
    __builtin_amdgcn_sched_barrier(0); \
    asm volatile("s_waitcnt vmcnt(4)" ::: "memory"); \
    __builtin_amdgcn_s_barrier(); \
  } while (0)

#define PH_SYNC_POST_VM0 do { \
    __builtin_amdgcn_s_setprio(0); \
    __builtin_amdgcn_sched_barrier(0); \
    asm volatile("s_waitcnt vmcnt(0)" ::: "memory"); \
    __builtin_amdgcn_s_barrier(); \
  } while (0)

__global__ __launch_bounds__(512, 1) void gemm8p(
    const __hip_bfloat16* __restrict__ A_, const __hip_bfloat16* __restrict__ B_,
    __hip_bfloat16* __restrict__ pre, __hip_bfloat16* __restrict__ adb,
    __hip_bfloat16* __restrict__ gdb) {
  __shared__ alignas(16) char smem[131072];
  const int tid = threadIdx.x, lane = tid & 63;
  const int wid = tid >> 6;
  const int wm = (wid >> 2) * 128, wn = (wid & 3) * 64;
  const int lr = lane & 15, lg = lane >> 4;

  const int bid = blockIdx.x;
  const int swz = (bid & 7) * 26 + (bid >> 3);
  const int mt = swz / 13, nt = swz % 13;
  const int m0 = mt * 256, n0g = nt * 256;

  int ob0 = tid * 16;         ob0 ^= ((ob0 >> 9) & 1) << 5;
  int ob1 = (tid + 512) * 16; ob1 ^= ((ob1 >> 9) & 1) << 5;
  const int sr0 = ((ob0 >> 11) << 4) + ((ob0 >> 6) & 15);
  const int sc0 = ((ob0 >> 10) & 1) * 32 + ((ob0 & 63) >> 1);
  const int sr1 = ((ob1 >> 11) << 4) + ((ob1 >> 6) & 15);
  const int sc1 = ((ob1 >> 10) & 1) * 32 + ((ob1 & 63) >> 1);

  const int foff = lr * 64 + ((lg * 16) ^ ((lr & 8) << 2));
  const int bq = (wn & 64) * 128;
  const char* a0base = smem + (wm >> 7) * 16384 + foff;
  const char* a1base = smem + 65536 + (wm >> 7) * 16384 + foff;
  const char* b0base = smem + 32768 + (wn >> 7) * 16384 + bq + foff;
  const char* b1base = smem + 98304 + (wn >> 7) * 16384 + bq + foff;

  f32x4 acc[8][4];
#pragma unroll
  for (int i = 0; i < 8; ++i)
#pragma unroll
    for (int j = 0; j < 4; ++j) acc[i][j] = (f32x4)(0.f);

  bf16x8 a[4][2], b01[2][2], b23[2][2];

  STAGE(A_, m0,        0, 0);
  STAGE(A_, m0 + 128,  0, 16384);
  STAGE(B_, n0g,       0, 32768);
  STAGE(B_, n0g + 128, 0, 32768 + 16384);
  STAGE(B_, n0g,       64, 98304);
  STAGE(B_, n0g + 128, 64, 98304 + 16384);
  asm volatile("s_waitcnt vmcnt(4)" ::: "memory");
  __builtin_amdgcn_s_barrier();

#pragma unroll 1
  for (int it = 0; it < 15; ++it) {
    const int kA1 = (2 * it + 1) * 64;
    const int kN2 = (2 * it + 2) * 64;
    const int kB3 = (2 * it + 3) * 64;
    LD_A(a0base, 0, a);
    LD_B(b0base, 0, b01);
    STAGE(A_, m0, kA1, 65536);
    PH_SYNC_PRE; MM_Q(a, b01, 0, 0); PH_SYNC_POST;
    LD_B(b0base, 1, b23);
    STAGE(A_, m0 + 128, kA1, 65536 + 16384);
    PH_SYNC_PRE; MM_Q(a, b23, 0, 1); PH_SYNC_POST;
    LD_A(a0base, 1, a);
    STAGE(B_, n0g, kN2, 32768);
    PH_SYNC_PRE; MM_Q(a, b23, 1, 1); PH_SYNC_POST;
    STAGE(B_, n0g + 128, kN2, 32768 + 16384);
    PH_SYNC_PRE; MM_Q(a, b01, 1, 0); PH_SYNC_POST_VM4;
    LD_A(a1base, 0, a);
    LD_B(b1base, 0, b01);
    STAGE(A_, m0, kN2, 0);
    PH_SYNC_PRE; MM_Q(a, b01, 0, 0); PH_SYNC_POST;
    LD_B(b1base, 1, b23);
    STAGE(A_, m0 + 128, kN2, 16384);
    PH_SYNC_PRE; MM_Q(a, b23, 0, 1); PH_SYNC_POST;
    LD_A(a1base, 1, a);
    STAGE(B_, n0g, kB3, 98304);
    PH_SYNC_PRE; MM_Q(a, b23, 1, 1); PH_SYNC_POST;
    STAGE(B_, n0g + 128, kB3, 98304 + 16384);
    PH_SYNC_PRE; MM_Q(a, b01, 1, 0); PH_SYNC_POST_VM4;
  }

  {
    const int kT = 1984;
    LD_A(a0base, 0, a);
    LD_B(b0base, 0, b01);
    STAGE(A_, m0, kT, 65536);
    PH_SYNC_PRE; MM_Q(a, b01, 0, 0); PH_SYNC_POST;
    LD_B(b0base, 1, b23);
    STAGE(A_, m0 + 128, kT, 65536 + 16384);
    PH_SYNC_PRE; MM_Q(a, b23, 0, 1); PH_SYNC_POST;
    LD_A(a0base, 1, a);
    PH_SYNC_PRE; MM_Q(a, b23, 1, 1); PH_SYNC_POST;
    PH_SYNC_PRE; MM_Q(a, b01, 1, 0); PH_SYNC_POST_VM0;
    LD_A(a1base, 0, a);
    LD_B(b1base, 0, b01);
    MM_Q(a, b01, 0, 0);
    LD_B(b1base, 1, b23);
    MM_Q(a, b23, 0, 1);
    LD_A(a1base, 1, a);
    MM_Q(a, b23, 1, 1);
    MM_Q(a, b01, 1, 0);
  }

#pragma unroll
  for (int mf = 0; mf < 8; ++mf) {
    const int row0 = m0 + wm + mf * 16 + lg * 4;
#pragma unroll
    for (int nf = 0; nf < 4; ++nf) {
      const int c = n0g + wn + nf * 16 + lr;
#pragma unroll
      for (int r = 0; r < 4; ++r) {
        const __hip_bfloat16 v = __float2bfloat16(acc[mf][nf][r]);
        const size_t rr = (size_t)(row0 + r);
        if (c < 3072)      pre[rr * 3072 + c] = v;
        else if (c < 3200) adb[rr * 128 + (c - 3072)] = v;
        else               gdb[rr * 128 + (c - 3200)] = v;
      }
    }
  }
}

// ---------------------------------------------------------------------------
// gemm_bf16k (Wo path): C[M,N] = A[M,K] @ Bt[N,K]^T, BK=64, TSWZ-swizzled
// LDS tiles staged via pre-swizzled global sources (linear gload_lds dest).
// MFMA order identical to the BK=32 form (two sub-steps kk=0,32).
// ---------------------------------------------------------------------------
template <typename OutT>
__global__ __launch_bounds__(256) void gemm_bf16k(
    const __hip_bfloat16* __restrict__ A, const __hip_bfloat16* __restrict__ Bt,
    OutT* __restrict__ C, int N, int K) {
  __shared__ alignas(16) char sA[128 * 64 * 2];
  __shared__ alignas(16) char sB[128 * 64 * 2];
  const int tid = threadIdx.x;
  const int lane = tid & 63;
  const int m0 = blockIdx.y * 128, n0 = blockIdx.x * 128;
  const int wm = ((tid >> 6) >> 1) * 64, wn = ((tid >> 6) & 1) * 64;
  f32x4 acc[4][4];
#pragma unroll
  for (int i = 0; i < 4; ++i)
#pragma unroll
    for (int j = 0; j < 4; ++j) acc[i][j] = (f32x4)(0.f);
  // Pre-swizzled staging source coords: linear dest chunk (tid+256s)*16
  // holds logical (row = tid>>3 + 32s, col16 = (tid&7) ^ ((tid>>3)&7)).
  const int srow = tid >> 3;                         // + 32*s per pass
  const int scol = (((tid & 7) ^ ((tid >> 3) & 7)) << 3);  // bf16 elems
  const int lr = lane & 15, lg = lane >> 4;
  for (int k0 = 0; k0 < K; k0 += 64) {
    __syncthreads();
#pragma unroll
    for (int s = 0; s < 4; ++s)
      gload16(A + (size_t)(m0 + srow + 32 * s) * K + k0 + scol,
              sA + (tid + 256 * s) * 16);
#pragma unroll
    for (int s = 0; s < 4; ++s)
      gload16(Bt + (size_t)(n0 + srow + 32 * s) * K + k0 + scol,
              sB + (tid + 256 * s) * 16);
    __syncthreads();
#pragma unroll
    for (int kk = 0; kk < 64; kk += 32) {
      bf16x8 af[4], bfr[4];
#pragma unroll
      for (int i = 0; i < 4; ++i)
        af[i] = *(const bf16x8*)(sA + TSWZ(wm + i * 16 + lr, (kk + lg * 8) * 2));
#pragma unroll
      for (int j = 0; j < 4; ++j)
        bfr[j] = *(const bf16x8*)(sB + TSWZ(wn + j * 16 + lr, (kk + lg * 8) * 2));
#pragma unroll
      for (int i = 0; i < 4; ++i)
#pragma unroll
        for (int j = 0; j < 4; ++j)
          acc[i][j] = __builtin_amdgcn_mfma_f32_16x16x32_bf16(af[i], bfr[j], acc[i][j], 0, 0, 0);
    }
  }
  const int er = (lane >> 4) * 4, ec = lane & 15;
#pragma unroll
  for (int i = 0; i < 4; ++i) {
#pragma unroll
    for (int j = 0; j < 4; ++j) {
      int row = m0 + wm + i * 16 + er;
      int col = n0 + wn + j * 16 + ec;
#pragma unroll
      for (int r = 0; r < 4; ++r) {
        float v = acc[i][j][r];
        if constexpr (sizeof(OutT) == 2)
          C[(size_t)(row + r) * N + col] = __float2bfloat16(v);
        else
          C[(size_t)(row + r) * N + col] = v;
      }
    }
  }
}

// ---------------------------------------------------------------------------
// gemm_augu: z-muxed 128x128-tile GEMM over K=128.
//   z=0: a = ad@Wau; fused logsig -> per-64-chunk cumsum -> gc, glast
//   z=1: gd@Wgu -> gatef bf16.
// ---------------------------------------------------------------------------
__global__ __launch_bounds__(256) void gemm_augu(
    const __hip_bfloat16* __restrict__ ad, const __hip_bfloat16* __restrict__ gd,
    const __hip_bfloat16* __restrict__ Wau, const __hip_bfloat16* __restrict__ Wgu,
    float* __restrict__ gc, float* __restrict__ glast,
    __hip_bfloat16* __restrict__ gatef) {
  constexpr int N = 1024, K = 128;
  __shared__ alignas(16) char smraw[128 * 132 * 4];
  __hip_bfloat16* sA = (__hip_bfloat16*)smraw;
  __hip_bfloat16* sB = (__hip_bfloat16*)(smraw + 8192);
  float (*scan)[132] = (float(*)[132])smraw;

  const int z = blockIdx.z;
  const __hip_bfloat16* A = z ? gd : ad;
  const __hip_bfloat16* Bt = z ? Wgu : Wau;
  const int tid = threadIdx.x;
  const int lane = tid & 63;
  const int m0 = blockIdx.y * 128, n0 = blockIdx.x * 128;
  const int wm = ((tid >> 6) >> 1) * 64, wn = ((tid >> 6) & 1) * 64;
  f32x4 acc[4][4];
#pragma unroll
  for (int i = 0; i < 4; ++i)
#pragma unroll
    for (int j = 0; j < 4; ++j) acc[i][j] = (f32x4)(0.f);
  const int f0 = tid, f1 = tid + 256;
  const int r0 = f0 >> 2, c0 = (f0 & 3) * 8;
  const int r1 = f1 >> 2, c1 = (f1 & 3) * 8;
  const size_t aoff0 = (size_t)(m0 + r0) * K + c0;
  const size_t aoff1 = (size_t)(m0 + r1) * K + c1;
  const size_t boff0 = (size_t)(n0 + r0) * K + c0;
  const size_t boff1 = (size_t)(n0 + r1) * K + c1;
  const int lr = lane & 15, lk = (lane >> 4) * 8;
#pragma unroll
  for (int k0 = 0; k0 < K; k0 += 32) {
    __syncthreads();
    gload16(A + aoff0 + k0, &sA[f0 * 8]);
    gload16(A + aoff1 + k0, &sA[f1 * 8]);
    gload16(Bt + boff0 + k0, &sB[f0 * 8]);
    gload16(Bt + boff1 + k0, &sB[f1 * 8]);
    __syncthreads();
    bf16x8 af[4], bfr[4];
#pragma unroll
    for (int i = 0; i < 4; ++i)
      af[i] = *(const bf16x8*)&sA[(wm + i * 16 + lr) * 32 + lk];
#pragma unroll
    for (int j = 0; j < 4; ++j)
      bfr[j] = *(const bf16x8*)&sB[(wn + j * 16 + lr) * 32 + lk];
#pragma unroll
    for (int i = 0; i < 4; ++i)
#pragma unroll
      for (int j = 0; j < 4; ++j)
        acc[i][j] = __builtin_amdgcn_mfma_f32_16x16x32_bf16(af[i], bfr[j], acc[i][j], 0, 0, 0);
  }
  const int er = (lane >> 4) * 4, ec = lane & 15;
  if (z == 1) {
#pragma unroll
    for (int i = 0; i < 4; ++i)
#pragma unroll
      for (int j = 0; j < 4; ++j) {
        int row = m0 + wm + i * 16 + er;
        int col = n0 + wn + j * 16 + ec;
#pragma unroll
        for (int r = 0; r < 4; ++r)
          gatef[(size_t)(row + r) * N + col] = __float2bfloat16(acc[i][j][r]);
      }
    return;
  }
  __syncthreads();
#pragma unroll
  for (int i = 0; i < 4; ++i)
#pragma unroll
    for (int j = 0; j < 4; ++j) {
      int rowL = wm + i * 16 + er;
      int colL = wn + j * 16 + ec;
#pragma unroll
      for (int r = 0; r < 4; ++r) {
        float a = acc[i][j][r];
        float s = fmaxf(1.f / (1.f + __expf(-a)), 1e-6f);
        scan[rowL + r][colL] = __logf(s);
      }
    }
  __syncthreads();
  {
    const int d = tid & 127, c2 = tid >> 7;
    const int h = blockIdx.x;
    const int b = m0 >> 11, tb = m0 & 2047;
    const int bh = b * H_ + h;
    float run = 0.f;
    const size_t gbase = ((size_t)bh * T_ + tb + c2 * 64) * 128 + d;
    for (int r = 0; r < 64; ++r) {
      run += scan[c2 * 64 + r][d];
      gc[gbase + (size_t)r * 128] = run;
    }
    glast[((size_t)(bh * NT_ + (tb >> 6) + c2)) * 128 + d] = run;
  }
}

// ---------------------------------------------------------------------------
// prep: merged cvt_bf (x -> xb) + weight transpose-conversions.
// ---------------------------------------------------------------------------
__global__ __launch_bounds__(256) void prep(
    const float* __restrict__ x, const float* __restrict__ Wq,
    const float* __restrict__ Wk, const float* __restrict__ Wv,
    const float* __restrict__ Wad, const float* __restrict__ Wgd,
    const float* __restrict__ Wau, const float* __restrict__ Wgu,
    const float* __restrict__ Wo, __hip_bfloat16* __restrict__ xb,
    __hip_bfloat16* __restrict__ Wt_qkv, __hip_bfloat16* __restrict__ Wt_dg,
    __hip_bfloat16* __restrict__ Wt_aug, __hip_bfloat16* __restrict__ Wt_o) {
  __shared__ float tile[64][33];
  int bid = blockIdx.x;
  const int tid = threadIdx.x;
  if (bid < 8192) {
    size_t i = ((size_t)bid * 256 + tid) * 4;
    float4 v = *(const float4*)(x + i);
    union { __hip_bfloat16 hx[4]; uint2 u2; } pk_;
    pk_.hx[0] = __float2bfloat16(v.x);
    pk_.hx[1] = __float2bfloat16(v.y);
    pk_.hx[2] = __float2bfloat16(v.z);
    pk_.hx[3] = __float2bfloat16(v.w);
    *(uint2*)(xb + i) = pk_.u2;
    return;
  }
  bid -= 8192;
  const float* W; __hip_bfloat16* dst; int K, N, bx, by;
  if (bid < 3072) {
    int z = bid / 1024, r = bid % 1024;
    W = (z == 0) ? Wq : (z == 1) ? Wk : Wv;
    dst = Wt_qkv + (size_t)z * C_ * D_;
    K = D_; N = C_; bx = r & 31; by = r >> 5;
  } else if (bid < 3072 + 256) {
    int b2 = bid - 3072;
    int z = b2 >> 7, r = b2 & 127;
    W = z ? Wgd : Wad;
    dst = Wt_dg + (size_t)z * HD_ * D_;
    K = D_; N = HD_; bx = r & 3; by = r >> 2;
  } else if (bid < 3072 + 256 + 128) {
    int b2 = bid - 3328;
    int z = b2 >> 6, r = b2 & 63;
    W = z ? Wgu : Wau;
    dst = Wt_aug + (size_t)z * C_ * HD_;
    K = HD_; N = C_; bx = r & 31; by = r >> 5;
  } else {
    int b2 = bid - 3456;
    W = Wo; dst = Wt_o;
    K = C_; N = D_; bx = b2 & 63; by = b2 >> 6;
  }
  const int kb = by * 64, nb = bx * 32;
#pragma unroll
  for (int p = 0; p < 2; ++p) {
    const int kk = (tid >> 3) + p * 32;
    const int c4 = (tid & 7) * 4;
    float4 v = *(const float4*)(W + (size_t)(kb + kk) * N + nb + c4);
    tile[kk][c4 + 0] = v.x;
    tile[kk][c4 + 1] = v.y;
    tile[kk][c4 + 2] = v.z;
    tile[kk][c4 + 3] = v.w;
  }
  __syncthreads();
  {
    const int nn = tid >> 3, kk8 = (tid & 7) * 8;
    union { __hip_bfloat16 hx[8]; uint4 u4; } pk_;
#pragma unroll
    for (int e = 0; e < 8; ++e) pk_.hx[e] = __float2bfloat16(tile[kk8 + e][nn]);
    *(uint4*)(dst + (size_t)(nb + nn) * K + kb + kk8) = pk_.u4;
  }
}

// ---------------------------------------------------------------------------
// chunk_mid (fused conv + pairdot + solve + ppre), 512 threads, 512 blocks.
// ---------------------------------------------------------------------------
__global__ __launch_bounds__(512) void chunk_mid(
    const __hip_bfloat16* __restrict__ pre, const float* __restrict__ gc,
    const float* __restrict__ cqw, const float* __restrict__ cqb,
    const float* __restrict__ ckw, const float* __restrict__ ckb,
    const float* __restrict__ cvw, const float* __restrict__ cvb,
    __hip_bfloat16* __restrict__ qg, __hip_bfloat16* __restrict__ Aq,
    __hip_bfloat16* __restrict__ w_bf, __hip_bfloat16* __restrict__ u_bf,
    __hip_bfloat16* __restrict__ PT_bf) {
  __shared__ alignas(16) char smc[66560];
  char* kpL = smc;                                  // 16 KB (dead after P2a)
  char* vbL = smc + 16384;                          // 16 KB (dead after P2a)
  char* kmL = smc + 32768;                          // 16 KB (live thru P2b)
  float (*A_T)[68] = (float(*)[68])(smc + 49152);   // 17,408 B
  char* soluT = kpL;                                // bf16 [128 vd][64 i], swz
  char* kmT   = vbL;                                // bf16 [128 kd][64 i], swz

  const int tid = threadIdx.x;
  const int bhn = blockIdx.x;
  const int bh = bhn >> 5, n = bhn & 31;
  const int b = bh >> 3, h = bh & 7;
  const size_t gbase = ((size_t)bh * T_ + (size_t)n * BT_) * HD_;
  const int wv = tid >> 6, lane = tid & 63;
  const int lr = lane & 15, lg = lane >> 4;

  // ---- P0: fused conv (8 rows per wave, 2 channels per lane) ----
  {
    const int d0 = lane * 2;
    const int c0 = h * HD_ + d0;
    float qw[2][4], kw[2][4], vw[2][4], qb2[2], kb2[2], vb2[2];
#pragma unroll
    for (int e = 0; e < 2; ++e) {
      const int c = c0 + e;
#pragma unroll
      for (int j = 0; j < 4; ++j) {
        qw[e][j] = cqw[c * 4 + j];
        kw[e][j] = ckw[c * 4 + j];
        vw[e][j] = cvw[c * 4 + j];
      }
      qb2[e] = cqb[c]; kb2[e] = ckb[c]; vb2[e] = cvb[c];
    }
    const int tw0 = n * 64 + wv * 8;
    const size_t prow0 = ((size_t)b * T_ + tw0) * (3 * C_) + c0;
    float xm[3][3][2];
#pragma unroll
    for (int a = 0; a < 3; ++a)
#pragma unroll
      for (int g2 = 0; g2 < 3; ++g2) { xm[a][g2][0] = 0.f; xm[a][g2][1] = 0.f; }
#pragma unroll
    for (int g2 = 1; g2 <= 3; ++g2) {
      if (tw0 - g2 >= 0) {
        const __hip_bfloat16* pr = pre + (prow0 - (size_t)g2 * (3 * C_));
#pragma unroll
        for (int a = 0; a < 3; ++a) {
          uint u = *(const uint*)(pr + a * C_);
          xm[a][g2 - 1][0] = __bfloat162float(((const __hip_bfloat16*)&u)[0]);
          xm[a][g2 - 1][1] = __bfloat162float(((const __hip_bfloat16*)&u)[1]);
        }
      }
    }
#pragma unroll
    for (int i = 0; i < 8; ++i) {
      const int t = tw0 + i;
      const __hip_bfloat16* pr = pre + (prow0 + (size_t)i * (3 * C_));
      float x0[3][2];
#pragma unroll
      for (int a = 0; a < 3; ++a) {
        uint u = *(const uint*)(pr + a * C_);
        x0[a][0] = __bfloat162float(((const __hip_bfloat16*)&u)[0]);
        x0[a][1] = __bfloat162float(((const __hip_bfloat16*)&u)[1]);
      }
      float aq[2], ak[2], av[2];
#pragma unroll
      for (int e = 0; e < 2; ++e) {
        aq[e] = qb2[e] + qw[e][3] * x0[0][e];
        if (t > 0) aq[e] += qw[e][2] * xm[0][0][e];
        if (t > 1) aq[e] += qw[e][1] * xm[0][1][e];
        if (t > 2) aq[e] += qw[e][0] * xm[0][2][e];
        ak[e] = kb2[e] + kw[e][3] * x0[1][e];
        if (t > 0) ak[e] += kw[e][2] * xm[1][0][e];
        if (t > 1) ak[e] += kw[e][1] * xm[1][1][e];
        if (t > 2) ak[e] += kw[e][0] * xm[1][2][e];
        av[e] = vb2[e] + vw[e][3] * x0[2][e];
        if (t > 0) av[e] += vw[e][2] * xm[2][0][e];
        if (t > 1) av[e] += vw[e][1] * xm[2][1][e];
        if (t > 2) av[e] += vw[e][0] * xm[2][2][e];
      }
#pragma unroll
      for (int a = 0; a < 3; ++a) {
#pragma unroll
        for (int e = 0; e < 2; ++e) {
          xm[a][2][e] = xm[a][1][e];
          xm[a][1][e] = xm[a][0][e];
          xm[a][0][e] = x0[a][e];
        }
      }
      float ssq = aq[0] * aq[0] + aq[1] * aq[1];
      float ssk = ak[0] * ak[0] + ak[1] * ak[1];
#pragma unroll
      for (int o = 1; o < 64; o <<= 1) {
        ssq += __shfl_xor(ssq, o);
        ssk += __shfl_xor(ssk, o);
      }
      const float nq = fmaxf(sqrtf(ssq), 1e-12f);
      const float nk = fmaxf(sqrtf(ssk), 1e-12f);
      const int row = wv * 8 + i;
      const size_t oi = gbase + (size_t)row * 128 + d0;
      const float2 gv = *(const float2*)(gc + oi);
      union { __hip_bfloat16 hx[2]; uint u; } oq, okp, okm, ov;
#pragma unroll
      for (int e = 0; e < 2; ++e) {
        const float g = (e == 0) ? gv.x : gv.y;
        const float eg = __expf(g), emg = __expf(-g);
        oq.hx[e]  = __float2bfloat16(aq[e] / nq * eg);
        const float kn = ak[e] / nk;
        okp.hx[e] = __float2bfloat16(kn * eg);
        okm.hx[e] = __float2bfloat16(kn * emg);
        ov.hx[e]  = __float2bfloat16(av[e] * (1.f / (1.f + __expf(-av[e]))));
      }
      *(uint*)(qg + oi) = oq.u;
      *(uint*)(kpL + SWZ(row, d0 * 2)) = okp.u;
      *(uint*)(kmL + SWZ(row, d0 * 2)) = okm.u;
      *(uint*)(vbL + SWZ(row, d0 * 2)) = ov.u;
    }
  }
  __syncthreads();

  // ---- P1: MFMA pair products (4 waves/product, 16-row slices) ----
  {
    const int prod = wv >> 2, rh = wv & 3;
    f32x4 acc[4];
#pragma unroll
    for (int j = 0; j < 4; ++j) acc[j] = (f32x4)(0.f);
#pragma unroll
    for (int k0 = 0; k0 < 128; k0 += 32) {
      bf16x8 af, bfr[4];
      const int ar = rh * 16 + lr;
      if (prod == 0)
        af = *(const bf16x8*)(kmL + SWZ(ar, (k0 + lg * 8) * 2));
      else
        af = *(const bf16x8*)(qg + gbase + (size_t)ar * 128 + k0 + lg * 8);
#pragma unroll
      for (int j = 0; j < 4; ++j) {
        const int br = j * 16 + lr;
        bfr[j] = (prod == 0)
          ? *(const bf16x8*)(kpL + SWZ(br, (k0 + lg * 8) * 2))
          : *(const bf16x8*)(kmL + SWZ(br, (k0 + lg * 8) * 2));
      }
#pragma unroll
      for (int j = 0; j < 4; ++j)
        acc[j] = __builtin_amdgcn_mfma_f32_16x16x32_bf16(af, bfr[j], acc[j], 0, 0, 0);
    }
    if (prod == 0) {
#pragma unroll
      for (int j = 0; j < 4; ++j) {
        int row0 = rh * 16 + lg * 4;
        int col = j * 16 + lr;
        *(float4*)&A_T[col][row0] =
            make_float4(acc[j][0], acc[j][1], acc[j][2], acc[j][3]);
      }
    } else {
      __hip_bfloat16* dst = Aq + (size_t)bhn * 4096;
#pragma unroll
      for (int j = 0; j < 4; ++j)
#pragma unroll
        for (int r = 0; r < 4; ++r) {
          int row = rh * 16 + lg * 4 + r;
          int col = j * 16 + lr;
          float v = (col <= row) ? acc[j][r] : 0.f;
          dst[row * 64 + col] = __float2bfloat16(v);
        }
    }
  }
  __syncthreads();

  // ---- P2a: rhs from LDS into registers (kp for w-cols, vb for u-cols) ----
  float s[64];
  const int col = tid & 127;
  if (tid < 256) {
    const char* rhsL = (tid < 128) ? kpL : vbL;
#pragma unroll
    for (int i = 0; i < 64; ++i)
      s[i] = __bfloat162float(*(const __hip_bfloat16*)(rhsL + SWZ(i, col * 2)));
  }
  __syncthreads();   // kpL/vbL now dead -> soluT/kmT may overwrite

  // ---- P2b: solve (threads 0-255) || kmL->kmT transpose (threads 256-511) ----
  if (tid < 256) {
#pragma unroll
    for (int ib = 0; ib < 64; ib += 4) {
      const float s0 = s[ib];
      const float s1 = fmaf(-A_T[ib][ib + 1], s0, s[ib + 1]);
      const float s2 = fmaf(-A_T[ib + 1][ib + 2], s1,
                       fmaf(-A_T[ib][ib + 2], s0, s[ib + 2]));
      const float s3 = fmaf(-A_T[ib + 2][ib + 3], s2,
                       fmaf(-A_T[ib + 1][ib + 3], s1,
                       fmaf(-A_T[ib][ib + 3], s0, s[ib + 3])));
      s[ib + 1] = s1; s[ib + 2] = s2; s[ib + 3] = s3;
#pragma unroll
      for (int j4 = ib + 4; j4 < 64; j4 += 4) {
        float4 a0 = *(const float4*)&A_T[ib][j4];
        float4 a1 = *(const float4*)&A_T[ib + 1][j4];
        float4 a2 = *(const float4*)&A_T[ib + 2][j4];
        float4 a3 = *(const float4*)&A_T[ib + 3][j4];
        s[j4]     = fmaf(-a3.x, s3, fmaf(-a2.x, s2, fmaf(-a1.x, s1, fmaf(-a0.x, s0, s[j4]))));
        s[j4 + 1] = fmaf(-a3.y, s3, fmaf(-a2.y, s2, fmaf(-a1.y, s1, fmaf(-a0.y, s0, s[j4 + 1]))));
        s[j4 + 2] = fmaf(-a3.z, s3, fmaf(-a2.z, s2, fmaf(-a1.z, s1, fmaf(-a0.z, s0, s[j4 + 2]))));
        s[j4 + 3] = fmaf(-a3.w, s3, fmaf(-a2.w, s2, fmaf(-a1.w, s1, fmaf(-a0.w, s0, s[j4 + 3]))));
      }
    }
    if (tid < 128) {
#pragma unroll
      for (int i = 0; i < 64; ++i)
        w_bf[gbase + (size_t)i * 128 + col] = __float2bfloat16(s[i]);
    } else {
#pragma unroll
      for (int i = 0; i < 64; ++i)
        u_bf[gbase + (size_t)i * 128 + col] = __float2bfloat16(s[i]);
#pragma unroll
      for (int c8 = 0; c8 < 8; ++c8) {
        union { __hip_bfloat16 hx[8]; uint4 u4; } pk2;
#pragma unroll
        for (int e = 0; e < 8; ++e) pk2.hx[e] = __float2bfloat16(s[c8 * 8 + e]);
        *(uint4*)(soluT + TSWZ(col, c8 * 16)) = pk2.u4;
      }
    }
  } else {
    const int t2 = tid - 256;
    const int d = (t2 & 63) * 2;
    const int i0 = (t2 >> 6) * 16;
    __hip_bfloat16 rlo[16], rhi[16];
#pragma unroll
    for (int ii = 0; ii < 16; ++ii) {
      uint u = *(const uint*)(kmL + SWZ(i0 + ii, d * 2));
      rlo[ii] = ((const __hip_bfloat16*)&u)[0];
      rhi[ii] = ((const __hip_bfloat16*)&u)[1];
    }
    *(uint4*)(kmT + TSWZ(d, i0 * 2))          = *(uint4*)&rlo[0];
    *(uint4*)(kmT + TSWZ(d, i0 * 2 + 16))     = *(uint4*)&rlo[8];
    *(uint4*)(kmT + TSWZ(d + 1, i0 * 2))      = *(uint4*)&rhi[0];
    *(uint4*)(kmT + TSWZ(d + 1, i0 * 2 + 16)) = *(uint4*)&rhi[8];
  }
  __syncthreads();

  // ---- P3: PT[vd][kd] = sum_i soluT[vd][i]*kmT[kd][i] via MFMA ----
  {
    f32x4 acc[8];
#pragma unroll
    for (int j = 0; j < 8; ++j) acc[j] = (f32x4)(0.f);
    const int vd = wv * 16 + lr;
#pragma unroll
    for (int k0 = 0; k0 < 64; k0 += 32) {
      bf16x8 af = *(const bf16x8*)(soluT + TSWZ(vd, (k0 + lg * 8) * 2));
#pragma unroll
      for (int j = 0; j < 8; ++j) {
        const int kd = j * 16 + lr;
        bf16x8 bf_ = *(const bf16x8*)(kmT + TSWZ(kd, (k0 + lg * 8) * 2));
        acc[j] = __builtin_amdgcn_mfma_f32_16x16x32_bf16(af, bf_, acc[j], 0, 0, 0);
      }
    }
    __hip_bfloat16* dst = PT_bf + (size_t)bhn * 16384;
#pragma unroll
    for (int j = 0; j < 8; ++j)
#pragma unroll
      for (int r = 0; r < 4; ++r) {
        const int vdr = wv * 16 + lg * 4 + r;
        const int kd = j * 16 + lr;
        dst[vdr * 128 + kd] = __float2bfloat16(acc[j][r]);
      }
  }
}

// ---------------------------------------------------------------------------
// scan over chunks on PT layout (bf16 in, f32 accumulate), software-pipelined.
// ---------------------------------------------------------------------------
__global__ __launch_bounds__(128) void scan_pt(
    const __hip_bfloat16* __restrict__ PT_bf, const float* __restrict__ glast,
    __hip_bfloat16* __restrict__ STg, float* __restrict__ Sout) {
  int vd = blockIdx.x & 127;
  int bh = blockIdx.x >> 7;
  int kd = threadIdx.x;
  const size_t base = (((size_t)bh * NT_) * HD_ + vd) * HD_ + kd;
  const size_t gstep = (size_t)HD_ * HD_;
  const float* glp = glast + (size_t)bh * NT_ * 128 + kd;
  float s = 0.f;
  float p = __bfloat162float(PT_bf[base]);
  float gl = glp[0];
#pragma unroll 4
  for (int n = 0; n < NT_ - 1; ++n) {
    const float pn = __bfloat162float(PT_bf[base + (size_t)(n + 1) * gstep]);
    const float gn = glp[(size_t)(n + 1) * 128];
    STg[base + (size_t)n * gstep] = __float2bfloat16(s);
    s = (s + p) * __expf(gl);
    p = pn; gl = gn;
  }
  STg[base + (size_t)(NT_ - 1) * gstep] = __float2bfloat16(s);
  s = (s + p) * __expf(gl);
  Sout[((size_t)bh * HD_ + kd) * HD_ + vd] = s;
}

// ---------------------------------------------------------------------------
// chunk_tail (8-wave): waves own (row-half x col-quarter) 32x32 sub-tiles.
// ---------------------------------------------------------------------------
__global__ __launch_bounds__(512) void chunk_tail(
    const __hip_bfloat16* __restrict__ qg_bf, const __hip_bfloat16* __restrict__ w_bf,
    const __hip_bfloat16* __restrict__ u_bf, const __hip_bfloat16* __restrict__ Aq_bf,
    const __hip_bfloat16* __restrict__ STg, const __hip_bfloat16* __restrict__ gatef,
    const float* __restrict__ normw, __hip_bfloat16* __restrict__ o2b) {
  constexpr int XTS = 72;
  __shared__ __hip_bfloat16 XT[128 * XTS];
  __shared__ float red[64][4];
  __shared__ __hip_bfloat16 uS[64 * 128];   // async-staged u chunk (16 KB)
  const int tid = threadIdx.x;
  const int bhn = blockIdx.x;
  const int bh = bhn >> 5, n = bhn & 31;
  const int b = bh >> 3, h = bh & 7;
  const int t0 = n * 64, hoff = h * 128;
  const size_t gbase = ((size_t)bh * T_ + t0) * 128;
  const __hip_bfloat16* Sg = STg + (size_t)bhn * 16384;

  {
    const char* src = (const char*)(u_bf + gbase);
#pragma unroll
    for (int s = 0; s < 2; ++s)
      gload16(src + s * 8192 + tid * 16, ((char*)uS) + s * 8192 + tid * 16);
  }

  const int wv = tid >> 6, lane = tid & 63;
  const int lr = lane & 15, lg = lane >> 4;
  const int rowh = wv >> 2, colq = wv & 3;
  f32x4 accX[2][2], accO[2][2];
#pragma unroll
  for (int i = 0; i < 2; ++i)
#pragma unroll
    for (int j = 0; j < 2; ++j) { accX[i][j] = (f32x4)(0.f); accO[i][j] = (f32x4)(0.f); }

  const __hip_bfloat16* wrow = w_bf + gbase;
  const __hip_bfloat16* qrow = qg_bf + gbase;
#pragma unroll
  for (int k0 = 0; k0 < 128; k0 += 32) {
    bf16x8 aW[2], aQ[2], bS[2];
#pragma unroll
    for (int i = 0; i < 2; ++i) {
      aW[i] = *(const bf16x8*)(wrow + (size_t)(rowh * 32 + i * 16 + lr) * 128 + k0 + lg * 8);
      aQ[i] = *(const bf16x8*)(qrow + (size_t)(rowh * 32 + i * 16 + lr) * 128 + k0 + lg * 8);
    }
#pragma unroll
    for (int j = 0; j < 2; ++j)
      bS[j] = *(const bf16x8*)(Sg + (size_t)(colq * 32 + j * 16 + lr) * 128 + k0 + lg * 8);
#pragma unroll
    for (int i = 0; i < 2; ++i)
#pragma unroll
      for (int j = 0; j < 2; ++j) {
        accX[i][j] = __builtin_amdgcn_mfma_f32_16x16x32_bf16(aW[i], bS[j], accX[i][j], 0, 0, 0);
        accO[i][j] = __builtin_amdgcn_mfma_f32_16x16x32_bf16(aQ[i], bS[j], accO[i][j], 0, 0, 0);
      }
  }

  asm volatile("s_waitcnt vmcnt(0)" ::: "memory");
  __builtin_amdgcn_s_barrier();

#pragma unroll
  for (int i = 0; i < 2; ++i)
#pragma unroll
    for (int j = 0; j < 2; ++j) {
      int row0 = rowh * 32 + i * 16 + lg * 4;
      int col = colq * 32 + j * 16 + lr;
      union { __hip_bfloat16 hx[4]; uint2 u2; } xv;
#pragma unroll
      for (int r = 0; r < 4; ++r) {
        float uu = __bfloat162float(uS[(row0 + r) * 128 + col]);
        xv.hx[r] = __float2bfloat16(uu - accX[i][j][r]);
      }
      *(uint2*)&XT[col * XTS + row0] = xv.u2;
    }
  __syncthreads();

  const __hip_bfloat16* aqb = Aq_bf + (size_t)bhn * 4096;
#pragma unroll
  for (int k0 = 0; k0 < 64; k0 += 32) {
    bf16x8 aA[2], bX[2];
#pragma unroll
    for (int i = 0; i < 2; ++i)
      aA[i] = *(const bf16x8*)(aqb + (size_t)(rowh * 32 + i * 16 + lr) * 64 + k0 + lg * 8);
#pragma unroll
    for (int j = 0; j < 2; ++j)
      bX[j] = *(const bf16x8*)&XT[(colq * 32 + j * 16 + lr) * XTS + k0 + lg * 8];
#pragma unroll
    for (int i = 0; i < 2; ++i)
#pragma unroll
      for (int j = 0; j < 2; ++j)
        accO[i][j] = __builtin_amdgcn_mfma_f32_16x16x32_bf16(aA[i], bX[j], accO[i][j], 0, 0, 0);
  }

#pragma unroll
  for (int i = 0; i < 2; ++i)
#pragma unroll
    for (int r = 0; r < 4; ++r) {
      int row = rowh * 32 + i * 16 + lg * 4 + r;
      float o0 = accO[i][0][r], o1 = accO[i][1][r];
      float ss = o0 * o0 + o1 * o1;
#pragma unroll
      for (int o = 1; o < 16; o <<= 1) ss += __shfl_xor(ss, o);
      if (lr == 0) red[row][colq] = ss;
    }
  __syncthreads();
  float nw0 = normw[colq * 32 + lr];
  float nw1 = normw[colq * 32 + 16 + lr];
#pragma unroll
  for (int i = 0; i < 2; ++i)
#pragma unroll
    for (int r = 0; r < 4; ++r) {
      int row = rowh * 32 + i * 16 + lg * 4 + r;
      float tot = red[row][0] + red[row][1] + red[row][2] + red[row][3];
      float rms = rsqrtf(tot * (1.f / 128.f) + EPS_RMS);
      size_t orow = (size_t)(b * T_ + t0 + row) * C_ + hoff;
      int c0 = colq * 32 + lr, c1 = c0 + 16;
      float g0 = __bfloat162float(gatef[orow + c0]);
      float g1 = __bfloat162float(gatef[orow + c1]);
      float s0 = 1.f / (1.f + __expf(-g0));
      float s1 = 1.f / (1.f + __expf(-g1));
      o2b[orow + c0] = __float2bfloat16(accO[i][0][r] * rms * nw0 * s0);
      o2b[orow + c1] = __float2bfloat16(accO[i][1][r] * rms * nw1 * s1);
    }
}

// ---------------------------------------------------------------------------
extern "C" void kernel_launch(void* const* d_in, const int* in_sizes, int n_in,
                              void* d_out, int out_size, void* d_ws, size_t ws_size,
                              hipStream_t stream) {
  (void)in_sizes; (void)n_in; (void)out_size;
  const float* x    = (const float*)d_in[0];
  const float* Wq   = (const float*)d_in[1];
  const float* Wk   = (const float*)d_in[2];
  const float* Wv   = (const float*)d_in[3];
  const float* cqw  = (const float*)d_in[4];
  const float* cqb  = (const float*)d_in[5];
  const float* ckw  = (const float*)d_in[6];
  const float* ckb  = (const float*)d_in[7];
  const float* cvw  = (const float*)d_in[8];
  const float* cvb  = (const float*)d_in[9];
  const float* Wad  = (const float*)d_in[10];
  const float* Wau  = (const float*)d_in[11];
  // d_in[12] = Wb : dead code in reference
  const float* Wgd  = (const float*)d_in[13];
  const float* Wgu  = (const float*)d_in[14];
  const float* normw= (const float*)d_in[15];
  const float* Wo   = (const float*)d_in[16];

  float* outp = (float*)d_out;
  float* Sout = outp + (size_t)M_ * D_;

  const size_t SZ = (size_t)M_ * C_;  // 4,194,304 f32 units

  float* ws = (float*)d_ws;
  __hip_bfloat16* pre_qkv = (__hip_bfloat16*)(ws);                 // 1.5 SZ
  float* a_full = ws + 3 * SZ / 2;                                  // 1 SZ (o2b alias region)
  __hip_bfloat16* gatef = (__hip_bfloat16*)(ws + 5 * SZ / 2);       // 0.5 SZ
  float* gc_g = ws + 3 * SZ;                                        // 1 SZ
  __hip_bfloat16* qg_bf = (__hip_bfloat16*)(ws + 4 * SZ);           // 0.5 SZ
  __hip_bfloat16* w_bf  = (__hip_bfloat16*)(ws + 6 * SZ);           // 0.5 SZ
  __hip_bfloat16* u_bf  = (__hip_bfloat16*)(ws + 13 * SZ / 2);      // 0.5 SZ
  __hip_bfloat16* Aq_bf = (__hip_bfloat16*)(ws + 7 * SZ);           // 0.25 SZ
  float* glast = ws + 29 * SZ / 4;                                  // 65536 units
  __hip_bfloat16* PT_bf = (__hip_bfloat16*)(ws + 15 * SZ / 2);      // 1 SZ
  __hip_bfloat16* STg   = (__hip_bfloat16*)(ws + 17 * SZ / 2);      // 1 SZ
  __hip_bfloat16* xb    = (__hip_bfloat16*)(ws + 19 * SZ / 2);      // 1 SZ
  __hip_bfloat16* Wt_qkv = (__hip_bfloat16*)(ws + 21 * SZ / 2);     // 0.75 SZ
  size_t off = 21 * SZ / 2 + 3 * SZ / 4;
  __hip_bfloat16* Wt_dg  = (__hip_bfloat16*)(ws + off); off += 262144;  // contiguous after Wt_qkv
  __hip_bfloat16* Wt_aug = (__hip_bfloat16*)(ws + off); off += 131072;
  __hip_bfloat16* Wt_o   = (__hip_bfloat16*)(ws + off); off += 1048576;
  __hip_bfloat16* ad_bf  = (__hip_bfloat16*)(ws + off); off += 262144;
  __hip_bfloat16* gd_bf  = (__hip_bfloat16*)(ws + off); off += 262144;
  if (ws_size < off * sizeof(float)) return;

  __hip_bfloat16* o2b = (__hip_bfloat16*)a_full;  // a_full region reused for o2b
  __hip_bfloat16* Wt_au = Wt_aug;
  __hip_bfloat16* Wt_gu = Wt_aug + (size_t)C_ * HD_;

  // Phase 0: all bf16 conversions in one launch (64x32 transpose tiles)
  prep<<<12672, 256, 0, stream>>>(x, Wq, Wk, Wv, Wad, Wgd, Wau, Wgu, Wo,
                                  xb, Wt_qkv, Wt_dg, Wt_aug, Wt_o);

  // Phase 1: qkv + dg projection in one 8-phase 256^2 launch
  gemm8p<<<208, 512, 0, stream>>>(xb, Wt_qkv, pre_qkv, ad_bf, gd_bf);
  // au/gu projection; z=0 fuses the logsig + per-chunk cumsum (gc, glast)
  gemm_augu<<<dim3(C_ / 128, M_ / 128, 2), 256, 0, stream>>>(
      ad_bf, gd_bf, Wt_au, Wt_gu, gc_g, glast, gatef);

  // Phase 2+3: fused conv + pairdot + solve + ppre, then state scan
  chunk_mid<<<B_ * H_ * NT_, 512, 0, stream>>>(pre_qkv, gc_g, cqw, cqb, ckw, ckb,
                                               cvw, cvb, qg_bf, Aq_bf, w_bf,
                                               u_bf, PT_bf);
  scan_pt<<<B_ * H_ * HD_, 128, 0, stream>>>(PT_bf, glast, STg, Sout);

  // Phase 4: fused output tail (8-wave) + projection (BK=64 swizzled)
  chunk_tail<<<B_ * H_ * NT_, 512, 0, stream>>>(qg_bf, w_bf, u_bf, Aq_bf, STg,
                                                gatef, normw, o2b);
  gemm_bf16k<float><<<dim3(D_ / 128, M_ / 128), 256, 0, stream>>>(o2b, Wt_o, outp, D_, C_);
}